// Round 1
// baseline (291.721 us; speedup 1.0000x reference)
//
#include <hip/hip_runtime.h>
#include <hip/hip_bf16.h>
#include <math.h>

#define Cdim 256
#define Hn 8
#define Bn 2
#define Sn 4096
#define Dh 32
#define GN_EPS 1e-5f
#define QK_SCALE 0.42044820762685725f  // 32^(-1/4), applied to BOTH q and k like the reference

typedef __attribute__((ext_vector_type(8))) short short8;
typedef __attribute__((ext_vector_type(4))) float floatx4;

__device__ __forceinline__ unsigned short f2bu(float x) {
  union { float f; unsigned u; } v; v.f = x;
  unsigned r = v.u + 0x7fffu + ((v.u >> 16) & 1u);  // RNE
  return (unsigned short)(r >> 16);
}

// ---------------- weights fp32 -> bf16 ----------------
__global__ void k_cast_w(const float* __restrict__ wq, const float* __restrict__ wk,
                         const float* __restrict__ wv, const float* __restrict__ wo,
                         unsigned short* __restrict__ wall) {
  int i = blockIdx.x * 256 + threadIdx.x;  // 65536 total
  wall[0 * 65536 + i] = f2bu(wq[i]);
  wall[1 * 65536 + i] = f2bu(wk[i]);
  wall[2 * 65536 + i] = f2bu(wv[i]);
  wall[3 * 65536 + i] = f2bu(wo[i]);
}

// ---------------- GroupNorm stats (deterministic two-stage) ----------------
__global__ void k_stats1(const float* __restrict__ x, float* __restrict__ part) {
  int b = blockIdx.x >> 8;
  int base = (blockIdx.x & 255) * 4096 + b * (Cdim * Sn);
  float s = 0.f, ss = 0.f;
#pragma unroll
  for (int k = 0; k < 16; ++k) {
    float v = x[base + k * 256 + threadIdx.x];
    s += v; ss += v * v;
  }
  for (int off = 32; off; off >>= 1) { s += __shfl_down(s, off); ss += __shfl_down(ss, off); }
  __shared__ float as[4], bs[4];
  int w = threadIdx.x >> 6;
  if ((threadIdx.x & 63) == 0) { as[w] = s; bs[w] = ss; }
  __syncthreads();
  if (threadIdx.x == 0) {
    part[blockIdx.x * 2]     = as[0] + as[1] + as[2] + as[3];
    part[blockIdx.x * 2 + 1] = bs[0] + bs[1] + bs[2] + bs[3];
  }
}

__global__ void k_stats2(const float* __restrict__ part, float* __restrict__ stats) {
  int b = blockIdx.x;
  float s  = part[(b * 256 + threadIdx.x) * 2];
  float ss = part[(b * 256 + threadIdx.x) * 2 + 1];
  for (int off = 32; off; off >>= 1) { s += __shfl_down(s, off); ss += __shfl_down(ss, off); }
  __shared__ float as[4], bs[4];
  int w = threadIdx.x >> 6;
  if ((threadIdx.x & 63) == 0) { as[w] = s; bs[w] = ss; }
  __syncthreads();
  if (threadIdx.x == 0) {
    float sum = as[0] + as[1] + as[2] + as[3];
    float sq  = bs[0] + bs[1] + bs[2] + bs[3];
    const float invN = 1.f / (float)(Cdim * Sn);
    float mean = sum * invN;
    float var  = sq * invN - mean * mean;
    stats[b * 2]     = mean;
    stats[b * 2 + 1] = rsqrtf(var + GN_EPS);
  }
}

// ---------------- normalize + transpose [B,C,S] -> bf16 [B,S,C] ----------------
__global__ void k_norm(const float* __restrict__ x, const float* __restrict__ gw,
                       const float* __restrict__ gb, const float* __restrict__ stats,
                       unsigned short* __restrict__ h) {
  int b = blockIdx.z, c0 = blockIdx.y * 64, s0 = blockIdx.x * 64;
  float mean = stats[b * 2], rstd = stats[b * 2 + 1];
  __shared__ unsigned short t[64][66];
  int lane = threadIdx.x & 63, rg = threadIdx.x >> 6;
#pragma unroll
  for (int i = 0; i < 16; ++i) {
    int cl = i * 4 + rg;
    float v = x[((size_t)(b * Cdim + c0 + cl)) * Sn + s0 + lane];
    float y = (v - mean) * rstd * gw[c0 + cl] + gb[c0 + cl];
    t[lane][cl] = f2bu(y);
  }
  __syncthreads();
#pragma unroll
  for (int i = 0; i < 16; ++i) {
    int sl = i * 4 + rg;
    h[((size_t)(b * Sn + s0 + sl)) * Cdim + c0 + lane] = t[sl][lane];
  }
}

// ---------------- QKV projection: h @ W^T + b ----------------
// q,k stored bf16 [B,H,S,32] scaled by QK_SCALE; v stored transposed bf16 [B,H,32,S]
__global__ void k_qkv(const unsigned short* __restrict__ h, const unsigned short* __restrict__ wall,
                      const float* __restrict__ bq, const float* __restrict__ bk,
                      const float* __restrict__ bv,
                      unsigned short* __restrict__ qf, unsigned short* __restrict__ kf,
                      unsigned short* __restrict__ vt) {
  int w = threadIdx.x >> 6, lane = threadIdx.x & 63;
  int lr = lane & 15, lg = lane >> 4;
  int m0 = blockIdx.x * 64 + w * 16;
  int proj = blockIdx.y >> 2, n0 = (blockIdx.y & 3) * 64;
  const unsigned short* W = wall + proj * 65536;
  floatx4 acc[4] = {};
  for (int k0 = 0; k0 < 256; k0 += 32) {
    short8 a = *(const short8*)(h + (size_t)(m0 + lr) * 256 + k0 + lg * 8);
#pragma unroll
    for (int nt = 0; nt < 4; ++nt) {
      short8 bfr = *(const short8*)(W + (size_t)(n0 + nt * 16 + lr) * 256 + k0 + lg * 8);
      acc[nt] = __builtin_amdgcn_mfma_f32_16x16x32_bf16(a, bfr, acc[nt], 0, 0, 0);
    }
  }
  __shared__ float tl[64][65];
  if (proj < 2) {
    const float* bias = proj ? bk : bq;
    unsigned short* dst = proj ? kf : qf;
#pragma unroll
    for (int nt = 0; nt < 4; ++nt) {
      int n = n0 + nt * 16 + lr;
      int hh = n >> 5, dd = n & 31;
      float bias_n = bias[n];
#pragma unroll
      for (int j = 0; j < 4; ++j) {
        int m = m0 + lg * 4 + j;
        int bb = m >> 12, s = m & 4095;
        float val = (acc[nt][j] + bias_n) * QK_SCALE;
        dst[(((size_t)(bb * Hn + hh)) * Sn + s) * Dh + dd] = f2bu(val);
      }
    }
  } else {
#pragma unroll
    for (int nt = 0; nt < 4; ++nt) {
      int nl = nt * 16 + lr;
      float bias_n = bv[n0 + nl];
#pragma unroll
      for (int j = 0; j < 4; ++j)
        tl[nl][w * 16 + lg * 4 + j] = acc[nt][j] + bias_n;
    }
    __syncthreads();
    int mBase = blockIdx.x * 64;
#pragma unroll
    for (int i = 0; i < 16; ++i) {
      int nl = i * 4 + (threadIdx.x >> 6);
      int ml = threadIdx.x & 63;
      int n = n0 + nl, m = mBase + ml;
      int bb = m >> 12, s = m & 4095;
      int hh = n >> 5, dd = n & 31;
      vt[(((size_t)(bb * Hn + hh)) * Dh + dd) * Sn + s] = f2bu(tl[nl][ml]);
    }
  }
}

// ---------------- flash attention: per wave 16 queries, KBLK=32 ----------------
__global__ void k_flash(const unsigned short* __restrict__ qf, const unsigned short* __restrict__ kf,
                        const unsigned short* __restrict__ vt, unsigned short* __restrict__ of) {
  int w = threadIdx.x >> 6, lane = threadIdx.x & 63;
  int lr = lane & 15, lg = lane >> 4;
  int bh = blockIdx.y;
  int q0 = blockIdx.x * 64 + w * 16;
  const unsigned short* Q = qf + (size_t)bh * Sn * Dh;
  const unsigned short* K = kf + (size_t)bh * Sn * Dh;
  const unsigned short* V = vt + (size_t)bh * Dh * Sn;
  short8 qa = *(const short8*)(Q + (size_t)(q0 + lr) * Dh + lg * 8);
  float mrow[4] = {-1e30f, -1e30f, -1e30f, -1e30f};
  float lrow[4] = {0.f, 0.f, 0.f, 0.f};
  floatx4 acc0 = {}, acc1 = {};
  const floatx4 zero = {};
  __shared__ unsigned short plds[4][16][32];
  for (int k0 = 0; k0 < Sn; k0 += 32) {
    short8 kb0 = *(const short8*)(K + (size_t)(k0 + lr) * Dh + lg * 8);
    short8 kb1 = *(const short8*)(K + (size_t)(k0 + 16 + lr) * Dh + lg * 8);
    short8 vb0 = *(const short8*)(V + (size_t)lr * Sn + k0 + lg * 8);
    short8 vb1 = *(const short8*)(V + (size_t)(16 + lr) * Sn + k0 + lg * 8);
    floatx4 s0 = __builtin_amdgcn_mfma_f32_16x16x32_bf16(qa, kb0, zero, 0, 0, 0);
    floatx4 s1 = __builtin_amdgcn_mfma_f32_16x16x32_bf16(qa, kb1, zero, 0, 0, 0);
    float rj[4];
#pragma unroll
    for (int j = 0; j < 4; ++j) {
      float mx = fmaxf(s0[j], s1[j]);
      mx = fmaxf(mx, __shfl_xor(mx, 1));
      mx = fmaxf(mx, __shfl_xor(mx, 2));
      mx = fmaxf(mx, __shfl_xor(mx, 4));
      mx = fmaxf(mx, __shfl_xor(mx, 8));
      float mn = fmaxf(mrow[j], mx);
      float p0 = __expf(s0[j] - mn), p1 = __expf(s1[j] - mn);
      float r = __expf(mrow[j] - mn);
      mrow[j] = mn;
      float ps = p0 + p1;
      ps += __shfl_xor(ps, 1);
      ps += __shfl_xor(ps, 2);
      ps += __shfl_xor(ps, 4);
      ps += __shfl_xor(ps, 8);
      lrow[j] = lrow[j] * r + ps;
      rj[j] = r;
      plds[w][lg * 4 + j][lr]      = f2bu(p0);
      plds[w][lg * 4 + j][16 + lr] = f2bu(p1);
    }
#pragma unroll
    for (int j = 0; j < 4; ++j) { acc0[j] *= rj[j]; acc1[j] *= rj[j]; }
    short8 pa = *(const short8*)(&plds[w][lr][lg * 8]);
    acc0 = __builtin_amdgcn_mfma_f32_16x16x32_bf16(pa, vb0, acc0, 0, 0, 0);
    acc1 = __builtin_amdgcn_mfma_f32_16x16x32_bf16(pa, vb1, acc1, 0, 0, 0);
  }
  int bb = bh >> 3, hh = bh & 7;
#pragma unroll
  for (int j = 0; j < 4; ++j) {
    float inv = 1.0f / lrow[j];
    size_t row = (size_t)bb * Sn + q0 + lg * 4 + j;
    of[row * Cdim + hh * Dh + lr]      = f2bu(acc0[j] * inv);
    of[row * Cdim + hh * Dh + 16 + lr] = f2bu(acc1[j] * inv);
  }
}

// ---------------- output projection + residual, write f32 [B,C,S] ----------------
__global__ void k_oproj(const unsigned short* __restrict__ of, const unsigned short* __restrict__ wo,
                        const float* __restrict__ bo, const float* __restrict__ x,
                        float* __restrict__ out) {
  int w = threadIdx.x >> 6, lane = threadIdx.x & 63;
  int lr = lane & 15, lg = lane >> 4;
  int m0 = blockIdx.x * 64 + w * 16;
  int n0 = blockIdx.y * 64;
  floatx4 acc[4] = {};
  for (int k0 = 0; k0 < 256; k0 += 32) {
    short8 a = *(const short8*)(of + (size_t)(m0 + lr) * 256 + k0 + lg * 8);
#pragma unroll
    for (int nt = 0; nt < 4; ++nt) {
      short8 bfr = *(const short8*)(wo + (size_t)(n0 + nt * 16 + lr) * 256 + k0 + lg * 8);
      acc[nt] = __builtin_amdgcn_mfma_f32_16x16x32_bf16(a, bfr, acc[nt], 0, 0, 0);
    }
  }
  __shared__ float tl[64][65];
#pragma unroll
  for (int nt = 0; nt < 4; ++nt) {
    float bias = bo[n0 + nt * 16 + lr];
#pragma unroll
    for (int j = 0; j < 4; ++j)
      tl[w * 16 + lg * 4 + j][nt * 16 + lr] = acc[nt][j] + bias;
  }
  __syncthreads();
  int mBase = blockIdx.x * 64;
#pragma unroll
  for (int i = 0; i < 16; ++i) {
    int cl = i * 4 + (threadIdx.x >> 6);
    int ml = threadIdx.x & 63;
    int m = mBase + ml;
    int bb = m >> 12, s = m & 4095;
    size_t oi = ((size_t)(bb * Cdim + n0 + cl)) * Sn + s;
    out[oi] = tl[ml][cl] + x[oi];
  }
}

extern "C" void kernel_launch(void* const* d_in, const int* in_sizes, int n_in,
                              void* d_out, int out_size, void* d_ws, size_t ws_size,
                              hipStream_t stream) {
  const float* x  = (const float*)d_in[0];
  const float* gw = (const float*)d_in[1];
  const float* gb = (const float*)d_in[2];
  const float* Wq = (const float*)d_in[3];
  const float* bq = (const float*)d_in[4];
  const float* Wk = (const float*)d_in[5];
  const float* bk = (const float*)d_in[6];
  const float* Wv = (const float*)d_in[7];
  const float* bv = (const float*)d_in[8];
  const float* Wo = (const float*)d_in[9];
  const float* bo = (const float*)d_in[10];
  float* out = (float*)d_out;
  char* ws = (char*)d_ws;
  if (ws_size < 0x1482000) return;  // need ~20.5 MB scratch

  float* part  = (float*)(ws);              // 512*2 f32
  float* stats = (float*)(ws + 0x1000);     // mean,rstd per batch
  unsigned short* wall = (unsigned short*)(ws + 0x2000);    // 4 x 256x256 bf16
  unsigned short* h  = (unsigned short*)(ws + 0x82000);     // [B*S, C] bf16
  unsigned short* qf = (unsigned short*)(ws + 0x482000);    // [B,H,S,32] bf16 (scaled)
  unsigned short* kf = (unsigned short*)(ws + 0x882000);    // [B,H,S,32] bf16 (scaled)
  unsigned short* vt = (unsigned short*)(ws + 0xC82000);    // [B,H,32,S] bf16
  unsigned short* of = (unsigned short*)(ws + 0x1082000);   // [B*S, C] bf16

  hipLaunchKernelGGL(k_cast_w, dim3(256), dim3(256), 0, stream, Wq, Wk, Wv, Wo, wall);
  hipLaunchKernelGGL(k_stats1, dim3(512), dim3(256), 0, stream, x, part);
  hipLaunchKernelGGL(k_stats2, dim3(2), dim3(256), 0, stream, part, stats);
  hipLaunchKernelGGL(k_norm, dim3(64, 4, 2), dim3(256), 0, stream, x, gw, gb, stats, h);
  hipLaunchKernelGGL(k_qkv, dim3(128, 12), dim3(256), 0, stream, h, wall, bq, bk, bv, qf, kf, vt);
  hipLaunchKernelGGL(k_flash, dim3(64, 16), dim3(256), 0, stream, qf, kf, vt, of);
  hipLaunchKernelGGL(k_oproj, dim3(128, 4), dim3(256), 0, stream, of, wall + 3 * 65536, bo, x, out);
}

// Round 2
// 168.635 us; speedup vs baseline: 1.7299x; 1.7299x over previous
//
#include <hip/hip_runtime.h>
#include <hip/hip_bf16.h>
#include <math.h>

#define Cdim 256
#define Hn 8
#define Bn 2
#define Sn 4096
#define Dh 32
#define GN_EPS 1e-5f
#define QK_SCALE 0.42044820762685725f   // 32^(-1/4), applied to BOTH q and k like the reference
#define LOG2E 1.4426950408889634f

typedef __attribute__((ext_vector_type(8))) short short8;
typedef __attribute__((ext_vector_type(4))) float floatx4;
typedef __attribute__((ext_vector_type(16))) float floatx16;

__device__ __forceinline__ unsigned short f2bu(float x) {
  union { float f; unsigned u; } v; v.f = x;
  unsigned r = v.u + 0x7fffu + ((v.u >> 16) & 1u);  // RNE
  return (unsigned short)(r >> 16);
}

// ---------------- weights fp32 -> bf16 ----------------
__global__ void k_cast_w(const float* __restrict__ wq, const float* __restrict__ wk,
                         const float* __restrict__ wv, const float* __restrict__ wo,
                         unsigned short* __restrict__ wall) {
  int i = blockIdx.x * 256 + threadIdx.x;  // 65536 total
  wall[0 * 65536 + i] = f2bu(wq[i]);
  wall[1 * 65536 + i] = f2bu(wk[i]);
  wall[2 * 65536 + i] = f2bu(wv[i]);
  wall[3 * 65536 + i] = f2bu(wo[i]);
}

// ---------------- GroupNorm stats (deterministic two-stage) ----------------
__global__ void k_stats1(const float* __restrict__ x, float* __restrict__ part) {
  int b = blockIdx.x >> 8;
  int base = (blockIdx.x & 255) * 4096 + b * (Cdim * Sn);
  float s = 0.f, ss = 0.f;
#pragma unroll
  for (int k = 0; k < 16; ++k) {
    float v = x[base + k * 256 + threadIdx.x];
    s += v; ss += v * v;
  }
  for (int off = 32; off; off >>= 1) { s += __shfl_down(s, off); ss += __shfl_down(ss, off); }
  __shared__ float as[4], bs[4];
  int w = threadIdx.x >> 6;
  if ((threadIdx.x & 63) == 0) { as[w] = s; bs[w] = ss; }
  __syncthreads();
  if (threadIdx.x == 0) {
    part[blockIdx.x * 2]     = as[0] + as[1] + as[2] + as[3];
    part[blockIdx.x * 2 + 1] = bs[0] + bs[1] + bs[2] + bs[3];
  }
}

__global__ void k_stats2(const float* __restrict__ part, float* __restrict__ stats) {
  int b = blockIdx.x;
  float s  = part[(b * 256 + threadIdx.x) * 2];
  float ss = part[(b * 256 + threadIdx.x) * 2 + 1];
  for (int off = 32; off; off >>= 1) { s += __shfl_down(s, off); ss += __shfl_down(ss, off); }
  __shared__ float as[4], bs[4];
  int w = threadIdx.x >> 6;
  if ((threadIdx.x & 63) == 0) { as[w] = s; bs[w] = ss; }
  __syncthreads();
  if (threadIdx.x == 0) {
    float sum = as[0] + as[1] + as[2] + as[3];
    float sq  = bs[0] + bs[1] + bs[2] + bs[3];
    const float invN = 1.f / (float)(Cdim * Sn);
    float mean = sum * invN;
    float var  = sq * invN - mean * mean;
    stats[b * 2]     = mean;
    stats[b * 2 + 1] = rsqrtf(var + GN_EPS);
  }
}

// ---------------- normalize + transpose [B,C,S] -> bf16 [B,S,C] ----------------
__global__ void k_norm(const float* __restrict__ x, const float* __restrict__ gw,
                       const float* __restrict__ gb, const float* __restrict__ stats,
                       unsigned short* __restrict__ h) {
  int b = blockIdx.z, c0 = blockIdx.y * 64, s0 = blockIdx.x * 64;
  float mean = stats[b * 2], rstd = stats[b * 2 + 1];
  __shared__ unsigned short t[64][66];
  int lane = threadIdx.x & 63, rg = threadIdx.x >> 6;
#pragma unroll
  for (int i = 0; i < 16; ++i) {
    int cl = i * 4 + rg;
    float v = x[((size_t)(b * Cdim + c0 + cl)) * Sn + s0 + lane];
    float y = (v - mean) * rstd * gw[c0 + cl] + gb[c0 + cl];
    t[lane][cl] = f2bu(y);
  }
  __syncthreads();
#pragma unroll
  for (int i = 0; i < 16; ++i) {
    int sl = i * 4 + rg;
    h[((size_t)(b * Sn + s0 + sl)) * Cdim + c0 + lane] = t[sl][lane];
  }
}

// ---------------- QKV projection: h @ W^T + b ----------------
// q bf16 [B,H,S,32] scaled by QK_SCALE*LOG2E; k bf16 [B,H,S,32] scaled by QK_SCALE;
// v stored transposed bf16 [B,H,32,S]
__global__ void k_qkv(const unsigned short* __restrict__ h, const unsigned short* __restrict__ wall,
                      const float* __restrict__ bq, const float* __restrict__ bk,
                      const float* __restrict__ bv,
                      unsigned short* __restrict__ qf, unsigned short* __restrict__ kf,
                      unsigned short* __restrict__ vt) {
  int w = threadIdx.x >> 6, lane = threadIdx.x & 63;
  int lr = lane & 15, lg = lane >> 4;
  int m0 = blockIdx.x * 64 + w * 16;
  int proj = blockIdx.y >> 2, n0 = (blockIdx.y & 3) * 64;
  const unsigned short* W = wall + proj * 65536;
  floatx4 acc[4] = {};
  for (int k0 = 0; k0 < 256; k0 += 32) {
    short8 a = *(const short8*)(h + (size_t)(m0 + lr) * 256 + k0 + lg * 8);
#pragma unroll
    for (int nt = 0; nt < 4; ++nt) {
      short8 bfr = *(const short8*)(W + (size_t)(n0 + nt * 16 + lr) * 256 + k0 + lg * 8);
      acc[nt] = __builtin_amdgcn_mfma_f32_16x16x32_bf16(a, bfr, acc[nt], 0, 0, 0);
    }
  }
  __shared__ float tl[64][65];
  if (proj < 2) {
    const float* bias = proj ? bk : bq;
    unsigned short* dst = proj ? kf : qf;
    float scale = proj ? QK_SCALE : (QK_SCALE * LOG2E);
#pragma unroll
    for (int nt = 0; nt < 4; ++nt) {
      int n = n0 + nt * 16 + lr;
      int hh = n >> 5, dd = n & 31;
      float bias_n = bias[n];
#pragma unroll
      for (int j = 0; j < 4; ++j) {
        int m = m0 + lg * 4 + j;
        int bb = m >> 12, s = m & 4095;
        float val = (acc[nt][j] + bias_n) * scale;
        dst[(((size_t)(bb * Hn + hh)) * Sn + s) * Dh + dd] = f2bu(val);
      }
    }
  } else {
#pragma unroll
    for (int nt = 0; nt < 4; ++nt) {
      int nl = nt * 16 + lr;
      float bias_n = bv[n0 + nl];
#pragma unroll
      for (int j = 0; j < 4; ++j)
        tl[nl][w * 16 + lg * 4 + j] = acc[nt][j] + bias_n;
    }
    __syncthreads();
    int mBase = blockIdx.x * 64;
#pragma unroll
    for (int i = 0; i < 16; ++i) {
      int nl = i * 4 + (threadIdx.x >> 6);
      int ml = threadIdx.x & 63;
      int n = n0 + nl, m = mBase + ml;
      int bb = m >> 12, s = m & 4095;
      int hh = n >> 5, dd = n & 31;
      vt[(((size_t)(bb * Hn + hh)) * Dh + dd) * Sn + s] = f2bu(tl[nl][ml]);
    }
  }
}

// ---------------- flash attention: 32x32 MFMA, swapped operands, in-register softmax ----
// scores arrive pre-scaled by log2(e): use exp2 throughout (log2 domain online softmax).
// Output written transposed: of2 [B,H,32,S] bf16.
__global__ void k_flash(const unsigned short* __restrict__ qf, const unsigned short* __restrict__ kf,
                        const unsigned short* __restrict__ vt, unsigned short* __restrict__ of2) {
  int w = threadIdx.x >> 6, lane = threadIdx.x & 63;
  int l31 = lane & 31, hi = lane >> 5;
  int bh = blockIdx.y;
  int q0 = (blockIdx.x * 4 + w) * 32;
  const unsigned short* Q = qf + (size_t)bh * Sn * Dh;
  const unsigned short* K = kf + (size_t)bh * Sn * Dh;
  const unsigned short* V = vt + (size_t)bh * Dh * Sn;

  // Q B-fragments: col q = l31, rows d = hi*8+0..7 (frag0: d 0..15, frag1: d 16..31)
  short8 qb0 = *(const short8*)(Q + (size_t)(q0 + l31) * Dh + hi * 8);
  short8 qb1 = *(const short8*)(Q + (size_t)(q0 + l31) * Dh + 16 + hi * 8);

  floatx16 oacc = {};          // O^T[d][q]: col q = l31, row d = (r&3)+8*(r>>2)+4*hi
  float m = -1e30f, l = 0.f;
  const floatx16 zero16 = {};
  const unsigned short* Vrow = V + (size_t)l31 * Sn;   // row d = l31 of V^T

  for (int k0 = 0; k0 < Sn; k0 += 32) {
    // K A-fragments: row k = l31, cols d = hi*8 (+16)
    short8 kb0 = *(const short8*)(K + (size_t)(k0 + l31) * Dh + hi * 8);
    short8 kb1 = *(const short8*)(K + (size_t)(k0 + l31) * Dh + 16 + hi * 8);
    // V^T A-fragments: row d = l31, cols k = k0 + hi*8 (+16)
    short8 vb0 = *(const short8*)(Vrow + k0 + hi * 8);
    short8 vb1 = *(const short8*)(Vrow + k0 + 16 + hi * 8);

    // S^T[k][q] = sum_d K[k][d] Q[q][d]  (already in log2 domain)
    floatx16 s = __builtin_amdgcn_mfma_f32_32x32x16_bf16(kb0, qb0, zero16, 0, 0, 0);
    s = __builtin_amdgcn_mfma_f32_32x32x16_bf16(kb1, qb1, s, 0, 0, 0);

    // lane holds 16 scores of q-row (l31); ks = (i&3)+8*(i>>2)+4*hi
    float mx = s[0];
#pragma unroll
    for (int i = 1; i < 16; ++i) mx = fmaxf(mx, s[i]);
    mx = fmaxf(mx, __shfl_xor(mx, 32));
    if (__any(mx > m + 8.f)) {          // defer-max: p bounded by 2^8
      float mn = fmaxf(m, mx);
      float r = __builtin_amdgcn_exp2f(m - mn);
      m = mn; l *= r;
#pragma unroll
      for (int i = 0; i < 16; ++i) oacc[i] *= r;
    }
    float p[16]; float sum = 0.f;
#pragma unroll
    for (int i = 0; i < 16; ++i) { p[i] = __builtin_amdgcn_exp2f(s[i] - m); sum += p[i]; }
    sum += __shfl_xor(sum, 32);
    l += sum;

    // pack P to bf16 and redistribute into P^T B-fragments via permlane32_swap (T12)
    unsigned c0, c1, c2, c3, c4, c5, c6, c7;
    asm("v_cvt_pk_bf16_f32 %0, %1, %2" : "=v"(c0) : "v"(p[0]),  "v"(p[1]));
    asm("v_cvt_pk_bf16_f32 %0, %1, %2" : "=v"(c1) : "v"(p[2]),  "v"(p[3]));
    asm("v_cvt_pk_bf16_f32 %0, %1, %2" : "=v"(c2) : "v"(p[4]),  "v"(p[5]));
    asm("v_cvt_pk_bf16_f32 %0, %1, %2" : "=v"(c3) : "v"(p[6]),  "v"(p[7]));
    asm("v_cvt_pk_bf16_f32 %0, %1, %2" : "=v"(c4) : "v"(p[8]),  "v"(p[9]));
    asm("v_cvt_pk_bf16_f32 %0, %1, %2" : "=v"(c5) : "v"(p[10]), "v"(p[11]));
    asm("v_cvt_pk_bf16_f32 %0, %1, %2" : "=v"(c6) : "v"(p[12]), "v"(p[13]));
    asm("v_cvt_pk_bf16_f32 %0, %1, %2" : "=v"(c7) : "v"(p[14]), "v"(p[15]));
    // swap: dst.hi-lanes <-> src.lo-lanes
    asm("v_permlane32_swap_b32 %0, %1" : "+v"(c0), "+v"(c2));
    asm("v_permlane32_swap_b32 %0, %1" : "+v"(c1), "+v"(c3));
    asm("v_permlane32_swap_b32 %0, %1" : "+v"(c4), "+v"(c6));
    asm("v_permlane32_swap_b32 %0, %1" : "+v"(c5), "+v"(c7));
    union { unsigned u[4]; short8 s8; } f0, f1;
    f0.u[0] = c0; f0.u[1] = c1; f0.u[2] = c2; f0.u[3] = c3;
    f1.u[0] = c4; f1.u[1] = c5; f1.u[2] = c6; f1.u[3] = c7;

    // O^T += V^T-chunk · P^T-chunk
    oacc = __builtin_amdgcn_mfma_f32_32x32x16_bf16(vb0, f0.s8, oacc, 0, 0, 0);
    oacc = __builtin_amdgcn_mfma_f32_32x32x16_bf16(vb1, f1.s8, oacc, 0, 0, 0);
  }

  float inv = 1.0f / l;
#pragma unroll
  for (int r = 0; r < 16; ++r) {
    int d = (r & 3) + 8 * (r >> 2) + 4 * hi;
    of2[((size_t)bh * Dh + d) * Sn + q0 + l31] = f2bu(oacc[r] * inv);
  }
}

// ---------------- output projection + residual: out[b,c,s] = Wo·of2 + bo + x ----------------
// of2 is [B, C'(=H*32), S]; A = Wo (c x c'), B = of2 (c' x s); D[c][s] direct, coalesced f32 out.
__global__ void k_oproj(const unsigned short* __restrict__ of2, const unsigned short* __restrict__ wo,
                        const float* __restrict__ bo, const float* __restrict__ x,
                        float* __restrict__ out) {
  int w = threadIdx.x >> 6, lane = threadIdx.x & 63;
  int lr = lane & 15, lg = lane >> 4;
  int b = blockIdx.z;
  int c0 = blockIdx.y * 64 + w * 16;
  int s0 = blockIdx.x * 16;
  const unsigned short* ofb = of2 + (size_t)b * Cdim * Sn;
  floatx4 acc = {};
  for (int k0 = 0; k0 < 256; k0 += 32) {
    short8 a = *(const short8*)(wo + (size_t)(c0 + lr) * 256 + k0 + lg * 8);
    short8 bfr;
#pragma unroll
    for (int j = 0; j < 8; ++j)
      bfr[j] = (short)ofb[(size_t)(k0 + lg * 8 + j) * Sn + s0 + lr];
    acc = __builtin_amdgcn_mfma_f32_16x16x32_bf16(a, bfr, acc, 0, 0, 0);
  }
#pragma unroll
  for (int j = 0; j < 4; ++j) {
    int c = c0 + lg * 4 + j;
    size_t oi = ((size_t)(b * Cdim + c)) * Sn + s0 + lr;
    out[oi] = acc[j] + bo[c] + x[oi];
  }
}

extern "C" void kernel_launch(void* const* d_in, const int* in_sizes, int n_in,
                              void* d_out, int out_size, void* d_ws, size_t ws_size,
                              hipStream_t stream) {
  const float* x  = (const float*)d_in[0];
  const float* gw = (const float*)d_in[1];
  const float* gb = (const float*)d_in[2];
  const float* Wq = (const float*)d_in[3];
  const float* bq = (const float*)d_in[4];
  const float* Wk = (const float*)d_in[5];
  const float* bk = (const float*)d_in[6];
  const float* Wv = (const float*)d_in[7];
  const float* bv = (const float*)d_in[8];
  const float* Wo = (const float*)d_in[9];
  const float* bo = (const float*)d_in[10];
  float* out = (float*)d_out;
  char* ws = (char*)d_ws;
  if (ws_size < 0x1482000) return;  // need ~20.5 MB scratch

  float* part  = (float*)(ws);              // 512*2 f32
  float* stats = (float*)(ws + 0x1000);     // mean,rstd per batch
  unsigned short* wall = (unsigned short*)(ws + 0x2000);    // 4 x 256x256 bf16
  unsigned short* h   = (unsigned short*)(ws + 0x82000);    // [B*S, C] bf16
  unsigned short* qf  = (unsigned short*)(ws + 0x482000);   // [B,H,S,32] bf16 (scaled, log2e folded)
  unsigned short* kf  = (unsigned short*)(ws + 0x882000);   // [B,H,S,32] bf16 (scaled)
  unsigned short* vt  = (unsigned short*)(ws + 0xC82000);   // [B,H,32,S] bf16
  unsigned short* of2 = (unsigned short*)(ws + 0x1082000);  // [B,H,32,S] bf16 (O transposed)

  hipLaunchKernelGGL(k_cast_w, dim3(256), dim3(256), 0, stream, Wq, Wk, Wv, Wo, wall);
  hipLaunchKernelGGL(k_stats1, dim3(512), dim3(256), 0, stream, x, part);
  hipLaunchKernelGGL(k_stats2, dim3(2), dim3(256), 0, stream, part, stats);
  hipLaunchKernelGGL(k_norm, dim3(64, 4, 2), dim3(256), 0, stream, x, gw, gb, stats, h);
  hipLaunchKernelGGL(k_qkv, dim3(128, 12), dim3(256), 0, stream, h, wall, bq, bk, bv, qf, kf, vt);
  hipLaunchKernelGGL(k_flash, dim3(32, 16), dim3(256), 0, stream, qf, kf, vt, of2);
  hipLaunchKernelGGL(k_oproj, dim3(256, 4, 2), dim3(256), 0, stream, of2, wall + 3 * 65536, bo, x, out);
}

// Round 3
// 157.575 us; speedup vs baseline: 1.8513x; 1.0702x over previous
//
#include <hip/hip_runtime.h>
#include <hip/hip_bf16.h>
#include <math.h>

#define Cdim 256
#define Hn 8
#define Bn 2
#define Sn 4096
#define Dh 32
#define GN_EPS 1e-5f
#define QK_SCALE 0.42044820762685725f   // 32^(-1/4), applied to BOTH q and k like the reference
#define LOG2E 1.4426950408889634f
#define NSPLIT 4
#define CHUNK (Sn / NSPLIT)             // 1024 keys per wave

typedef __attribute__((ext_vector_type(8))) short short8;
typedef __attribute__((ext_vector_type(4))) float floatx4;
typedef __attribute__((ext_vector_type(16))) float floatx16;

__device__ __forceinline__ unsigned short f2bu(float x) {
  union { float f; unsigned u; } v; v.f = x;
  unsigned r = v.u + 0x7fffu + ((v.u >> 16) & 1u);  // RNE
  return (unsigned short)(r >> 16);
}

// ---------------- weights fp32 -> bf16 ----------------
__global__ void k_cast_w(const float* __restrict__ wq, const float* __restrict__ wk,
                         const float* __restrict__ wv, const float* __restrict__ wo,
                         unsigned short* __restrict__ wall) {
  int i = blockIdx.x * 256 + threadIdx.x;  // 65536 total
  wall[0 * 65536 + i] = f2bu(wq[i]);
  wall[1 * 65536 + i] = f2bu(wk[i]);
  wall[2 * 65536 + i] = f2bu(wv[i]);
  wall[3 * 65536 + i] = f2bu(wo[i]);
}

// ---------------- GroupNorm stats (deterministic two-stage) ----------------
__global__ void k_stats1(const float* __restrict__ x, float* __restrict__ part) {
  int b = blockIdx.x >> 8;
  int base = (blockIdx.x & 255) * 4096 + b * (Cdim * Sn);
  float s = 0.f, ss = 0.f;
#pragma unroll
  for (int k = 0; k < 16; ++k) {
    float v = x[base + k * 256 + threadIdx.x];
    s += v; ss += v * v;
  }
  for (int off = 32; off; off >>= 1) { s += __shfl_down(s, off); ss += __shfl_down(ss, off); }
  __shared__ float as[4], bs[4];
  int w = threadIdx.x >> 6;
  if ((threadIdx.x & 63) == 0) { as[w] = s; bs[w] = ss; }
  __syncthreads();
  if (threadIdx.x == 0) {
    part[blockIdx.x * 2]     = as[0] + as[1] + as[2] + as[3];
    part[blockIdx.x * 2 + 1] = bs[0] + bs[1] + bs[2] + bs[3];
  }
}

__global__ void k_stats2(const float* __restrict__ part, float* __restrict__ stats) {
  int b = blockIdx.x;
  float s  = part[(b * 256 + threadIdx.x) * 2];
  float ss = part[(b * 256 + threadIdx.x) * 2 + 1];
  for (int off = 32; off; off >>= 1) { s += __shfl_down(s, off); ss += __shfl_down(ss, off); }
  __shared__ float as[4], bs[4];
  int w = threadIdx.x >> 6;
  if ((threadIdx.x & 63) == 0) { as[w] = s; bs[w] = ss; }
  __syncthreads();
  if (threadIdx.x == 0) {
    float sum = as[0] + as[1] + as[2] + as[3];
    float sq  = bs[0] + bs[1] + bs[2] + bs[3];
    const float invN = 1.f / (float)(Cdim * Sn);
    float mean = sum * invN;
    float var  = sq * invN - mean * mean;
    stats[b * 2]     = mean;
    stats[b * 2 + 1] = rsqrtf(var + GN_EPS);
  }
}

// ---------------- normalize + transpose [B,C,S] -> bf16 [B,S,C] ----------------
__global__ void k_norm(const float* __restrict__ x, const float* __restrict__ gw,
                       const float* __restrict__ gb, const float* __restrict__ stats,
                       unsigned short* __restrict__ h) {
  int b = blockIdx.z, c0 = blockIdx.y * 64, s0 = blockIdx.x * 64;
  float mean = stats[b * 2], rstd = stats[b * 2 + 1];
  __shared__ unsigned short t[64][66];
  int lane = threadIdx.x & 63, rg = threadIdx.x >> 6;
#pragma unroll
  for (int i = 0; i < 16; ++i) {
    int cl = i * 4 + rg;
    float v = x[((size_t)(b * Cdim + c0 + cl)) * Sn + s0 + lane];
    float y = (v - mean) * rstd * gw[c0 + cl] + gb[c0 + cl];
    t[lane][cl] = f2bu(y);
  }
  __syncthreads();
#pragma unroll
  for (int i = 0; i < 16; ++i) {
    int sl = i * 4 + rg;
    h[((size_t)(b * Sn + s0 + sl)) * Cdim + c0 + lane] = t[sl][lane];
  }
}

// ---------------- QKV projection: h @ W^T + b ----------------
// q bf16 [B,H,S,32] scaled by QK_SCALE*LOG2E; k bf16 [B,H,S,32] scaled by QK_SCALE;
// v stored transposed bf16 [B,H,32,S]
__global__ void k_qkv(const unsigned short* __restrict__ h, const unsigned short* __restrict__ wall,
                      const float* __restrict__ bq, const float* __restrict__ bk,
                      const float* __restrict__ bv,
                      unsigned short* __restrict__ qf, unsigned short* __restrict__ kf,
                      unsigned short* __restrict__ vt) {
  int w = threadIdx.x >> 6, lane = threadIdx.x & 63;
  int lr = lane & 15, lg = lane >> 4;
  int m0 = blockIdx.x * 64 + w * 16;
  int proj = blockIdx.y >> 2, n0 = (blockIdx.y & 3) * 64;
  const unsigned short* W = wall + proj * 65536;
  floatx4 acc[4] = {};
  for (int k0 = 0; k0 < 256; k0 += 32) {
    short8 a = *(const short8*)(h + (size_t)(m0 + lr) * 256 + k0 + lg * 8);
#pragma unroll
    for (int nt = 0; nt < 4; ++nt) {
      short8 bfr = *(const short8*)(W + (size_t)(n0 + nt * 16 + lr) * 256 + k0 + lg * 8);
      acc[nt] = __builtin_amdgcn_mfma_f32_16x16x32_bf16(a, bfr, acc[nt], 0, 0, 0);
    }
  }
  __shared__ float tl[64][65];
  if (proj < 2) {
    const float* bias = proj ? bk : bq;
    unsigned short* dst = proj ? kf : qf;
    float scale = proj ? QK_SCALE : (QK_SCALE * LOG2E);
#pragma unroll
    for (int nt = 0; nt < 4; ++nt) {
      int n = n0 + nt * 16 + lr;
      int hh = n >> 5, dd = n & 31;
      float bias_n = bias[n];
#pragma unroll
      for (int j = 0; j < 4; ++j) {
        int m = m0 + lg * 4 + j;
        int bb = m >> 12, s = m & 4095;
        float val = (acc[nt][j] + bias_n) * scale;
        dst[(((size_t)(bb * Hn + hh)) * Sn + s) * Dh + dd] = f2bu(val);
      }
    }
  } else {
#pragma unroll
    for (int nt = 0; nt < 4; ++nt) {
      int nl = nt * 16 + lr;
      float bias_n = bv[n0 + nl];
#pragma unroll
      for (int j = 0; j < 4; ++j)
        tl[nl][w * 16 + lg * 4 + j] = acc[nt][j] + bias_n;
    }
    __syncthreads();
    int mBase = blockIdx.x * 64;
#pragma unroll
    for (int i = 0; i < 16; ++i) {
      int nl = i * 4 + (threadIdx.x >> 6);
      int ml = threadIdx.x & 63;
      int n = n0 + nl, m = mBase + ml;
      int bb = m >> 12, s = m & 4095;
      int hh = n >> 5, dd = n & 31;
      vt[(((size_t)(bb * Hn + hh)) * Dh + dd) * Sn + s] = f2bu(tl[nl][ml]);
    }
  }
}

// ---------------- flash attention: split-K x4 within block, in-register softmax ----------
// 4 waves share one 32-query tile; wave w scans keys [w*1024, w*1024+1024); LDS combine.
// Scores pre-scaled by log2(e) -> exp2 online softmax. Output of2 [B,H,32,S] bf16.
__global__ void k_flash(const unsigned short* __restrict__ qf, const unsigned short* __restrict__ kf,
                        const unsigned short* __restrict__ vt, unsigned short* __restrict__ of2) {
  int w = threadIdx.x >> 6, lane = threadIdx.x & 63;
  int l31 = lane & 31, hi = lane >> 5;
  int bh = blockIdx.y;
  int q0 = blockIdx.x * 32;
  const unsigned short* Q = qf + (size_t)bh * Sn * Dh;
  const unsigned short* K = kf + (size_t)bh * Sn * Dh;
  const unsigned short* V = vt + (size_t)bh * Dh * Sn;

  // Q B-fragments: col q = l31, rows d = hi*8+0..7 (frag0: d 0..15, frag1: d 16..31)
  short8 qb0 = *(const short8*)(Q + (size_t)(q0 + l31) * Dh + hi * 8);
  short8 qb1 = *(const short8*)(Q + (size_t)(q0 + l31) * Dh + 16 + hi * 8);

  floatx16 oacc = {};          // O^T[d][q]: col q = l31, row d = (r&3)+8*(r>>2)+4*hi
  float m = -1e30f, l = 0.f;
  const floatx16 zero16 = {};
  const int kbase = w * CHUNK;
  const unsigned short* Kc = K + (size_t)kbase * Dh;
  const unsigned short* Vrow = V + (size_t)l31 * Sn + kbase;  // row d = l31 of V^T, chunk offset

  // prefetch step 0
  short8 kb0 = *(const short8*)(Kc + (size_t)l31 * Dh + hi * 8);
  short8 kb1 = *(const short8*)(Kc + (size_t)l31 * Dh + 16 + hi * 8);
  short8 vb0 = *(const short8*)(Vrow + hi * 8);
  short8 vb1 = *(const short8*)(Vrow + 16 + hi * 8);

  for (int it = 0; it < CHUNK / 32; ++it) {
    // S^T[k][q] = sum_d K[k][d] Q[q][d]  (log2 domain)
    floatx16 s = __builtin_amdgcn_mfma_f32_32x32x16_bf16(kb0, qb0, zero16, 0, 0, 0);
    s = __builtin_amdgcn_mfma_f32_32x32x16_bf16(kb1, qb1, s, 0, 0, 0);

    // prefetch next step (wrap at end; redundant last load stays in cache)
    int nx = (it + 1) & (CHUNK / 32 - 1);
    short8 nkb0 = *(const short8*)(Kc + (size_t)(nx * 32 + l31) * Dh + hi * 8);
    short8 nkb1 = *(const short8*)(Kc + (size_t)(nx * 32 + l31) * Dh + 16 + hi * 8);
    short8 nvb0 = *(const short8*)(Vrow + nx * 32 + hi * 8);
    short8 nvb1 = *(const short8*)(Vrow + nx * 32 + 16 + hi * 8);

    // lane holds 16 scores of q-row (l31); tree max
    float a0 = fmaxf(s[0], s[1]),  a1 = fmaxf(s[2], s[3]);
    float a2 = fmaxf(s[4], s[5]),  a3 = fmaxf(s[6], s[7]);
    float a4 = fmaxf(s[8], s[9]),  a5 = fmaxf(s[10], s[11]);
    float a6 = fmaxf(s[12], s[13]), a7 = fmaxf(s[14], s[15]);
    a0 = fmaxf(a0, a1); a2 = fmaxf(a2, a3); a4 = fmaxf(a4, a5); a6 = fmaxf(a6, a7);
    float mx = fmaxf(fmaxf(a0, a2), fmaxf(a4, a6));
    mx = fmaxf(mx, __shfl_xor(mx, 32));
    if (__any(mx > m + 8.f)) {          // defer-max: p bounded by 2^8
      float mn = fmaxf(m, mx);
      float r = __builtin_amdgcn_exp2f(m - mn);
      m = mn; l *= r;
#pragma unroll
      for (int i = 0; i < 16; ++i) oacc[i] *= r;
    }
    float p[16];
#pragma unroll
    for (int i = 0; i < 16; ++i) p[i] = __builtin_amdgcn_exp2f(s[i] - m);
    float t0 = (p[0] + p[1]) + (p[2] + p[3]);
    float t1 = (p[4] + p[5]) + (p[6] + p[7]);
    float t2 = (p[8] + p[9]) + (p[10] + p[11]);
    float t3 = (p[12] + p[13]) + (p[14] + p[15]);
    float sum = (t0 + t1) + (t2 + t3);
    sum += __shfl_xor(sum, 32);
    l += sum;

    // pack P to bf16 and redistribute into P^T B-fragments via permlane32_swap (T12)
    unsigned c0, c1, c2, c3, c4, c5, c6, c7;
    asm("v_cvt_pk_bf16_f32 %0, %1, %2" : "=v"(c0) : "v"(p[0]),  "v"(p[1]));
    asm("v_cvt_pk_bf16_f32 %0, %1, %2" : "=v"(c1) : "v"(p[2]),  "v"(p[3]));
    asm("v_cvt_pk_bf16_f32 %0, %1, %2" : "=v"(c2) : "v"(p[4]),  "v"(p[5]));
    asm("v_cvt_pk_bf16_f32 %0, %1, %2" : "=v"(c3) : "v"(p[6]),  "v"(p[7]));
    asm("v_cvt_pk_bf16_f32 %0, %1, %2" : "=v"(c4) : "v"(p[8]),  "v"(p[9]));
    asm("v_cvt_pk_bf16_f32 %0, %1, %2" : "=v"(c5) : "v"(p[10]), "v"(p[11]));
    asm("v_cvt_pk_bf16_f32 %0, %1, %2" : "=v"(c6) : "v"(p[12]), "v"(p[13]));
    asm("v_cvt_pk_bf16_f32 %0, %1, %2" : "=v"(c7) : "v"(p[14]), "v"(p[15]));
    asm("v_permlane32_swap_b32 %0, %1" : "+v"(c0), "+v"(c2));
    asm("v_permlane32_swap_b32 %0, %1" : "+v"(c1), "+v"(c3));
    asm("v_permlane32_swap_b32 %0, %1" : "+v"(c4), "+v"(c6));
    asm("v_permlane32_swap_b32 %0, %1" : "+v"(c5), "+v"(c7));
    union { unsigned u[4]; short8 s8; } f0, f1;
    f0.u[0] = c0; f0.u[1] = c1; f0.u[2] = c2; f0.u[3] = c3;
    f1.u[0] = c4; f1.u[1] = c5; f1.u[2] = c6; f1.u[3] = c7;

    // O^T += V^T-chunk · P^T-chunk
    oacc = __builtin_amdgcn_mfma_f32_32x32x16_bf16(vb0, f0.s8, oacc, 0, 0, 0);
    oacc = __builtin_amdgcn_mfma_f32_32x32x16_bf16(vb1, f1.s8, oacc, 0, 0, 0);

    kb0 = nkb0; kb1 = nkb1; vb0 = nvb0; vb1 = nvb1;
  }

  // ---- cross-wave combine via LDS ----
  __shared__ float ot[NSPLIT][16][64];
  __shared__ float lm[NSPLIT][2][32];
#pragma unroll
  for (int r = 0; r < 16; ++r) ot[w][r][lane] = oacc[r];
  if (!hi) { lm[w][0][l31] = m; lm[w][1][l31] = l; }
  __syncthreads();

  float m0 = lm[0][0][l31], m1 = lm[1][0][l31], m2 = lm[2][0][l31], m3 = lm[3][0][l31];
  float M = fmaxf(fmaxf(m0, m1), fmaxf(m2, m3));
  float r0 = __builtin_amdgcn_exp2f(m0 - M), r1 = __builtin_amdgcn_exp2f(m1 - M);
  float r2 = __builtin_amdgcn_exp2f(m2 - M), r3 = __builtin_amdgcn_exp2f(m3 - M);
  float L = lm[0][1][l31] * r0 + lm[1][1][l31] * r1 + lm[2][1][l31] * r2 + lm[3][1][l31] * r3;
  float invL = 1.0f / L;
#pragma unroll
  for (int rr = 0; rr < 4; ++rr) {
    int r = w * 4 + rr;
    float val = ot[0][r][lane] * r0 + ot[1][r][lane] * r1 +
                ot[2][r][lane] * r2 + ot[3][r][lane] * r3;
    int d = (r & 3) + 8 * (r >> 2) + 4 * hi;
    of2[((size_t)bh * Dh + d) * Sn + q0 + l31] = f2bu(val * invL);
  }
}

// ---------------- output projection + residual: out[b,c,s] = Wo·of2 + bo + x ----------------
// of2 is [B, C'(=H*32), S]; A = Wo (c x c'), B = of2 (c' x s); D[c][s] direct, coalesced f32 out.
__global__ void k_oproj(const unsigned short* __restrict__ of2, const unsigned short* __restrict__ wo,
                        const float* __restrict__ bo, const float* __restrict__ x,
                        float* __restrict__ out) {
  int w = threadIdx.x >> 6, lane = threadIdx.x & 63;
  int lr = lane & 15, lg = lane >> 4;
  int b = blockIdx.z;
  int c0 = blockIdx.y * 64 + w * 16;
  int s0 = blockIdx.x * 16;
  const unsigned short* ofb = of2 + (size_t)b * Cdim * Sn;
  floatx4 acc = {};
  for (int k0 = 0; k0 < 256; k0 += 32) {
    short8 a = *(const short8*)(wo + (size_t)(c0 + lr) * 256 + k0 + lg * 8);
    short8 bfr;
#pragma unroll
    for (int j = 0; j < 8; ++j)
      bfr[j] = (short)ofb[(size_t)(k0 + lg * 8 + j) * Sn + s0 + lr];
    acc = __builtin_amdgcn_mfma_f32_16x16x32_bf16(a, bfr, acc, 0, 0, 0);
  }
#pragma unroll
  for (int j = 0; j < 4; ++j) {
    int c = c0 + lg * 4 + j;
    size_t oi = ((size_t)(b * Cdim + c)) * Sn + s0 + lr;
    out[oi] = acc[j] + bo[c] + x[oi];
  }
}

extern "C" void kernel_launch(void* const* d_in, const int* in_sizes, int n_in,
                              void* d_out, int out_size, void* d_ws, size_t ws_size,
                              hipStream_t stream) {
  const float* x  = (const float*)d_in[0];
  const float* gw = (const float*)d_in[1];
  const float* gb = (const float*)d_in[2];
  const float* Wq = (const float*)d_in[3];
  const float* bq = (const float*)d_in[4];
  const float* Wk = (const float*)d_in[5];
  const float* bk = (const float*)d_in[6];
  const float* Wv = (const float*)d_in[7];
  const float* bv = (const float*)d_in[8];
  const float* Wo = (const float*)d_in[9];
  const float* bo = (const float*)d_in[10];
  float* out = (float*)d_out;
  char* ws = (char*)d_ws;
  if (ws_size < 0x1482000) return;  // need ~20.5 MB scratch

  float* part  = (float*)(ws);              // 512*2 f32
  float* stats = (float*)(ws + 0x1000);     // mean,rstd per batch
  unsigned short* wall = (unsigned short*)(ws + 0x2000);    // 4 x 256x256 bf16
  unsigned short* h   = (unsigned short*)(ws + 0x82000);    // [B*S, C] bf16
  unsigned short* qf  = (unsigned short*)(ws + 0x482000);   // [B,H,S,32] bf16 (scaled, log2e folded)
  unsigned short* kf  = (unsigned short*)(ws + 0x882000);   // [B,H,S,32] bf16 (scaled)
  unsigned short* vt  = (unsigned short*)(ws + 0xC82000);   // [B,H,32,S] bf16
  unsigned short* of2 = (unsigned short*)(ws + 0x1082000);  // [B,H,32,S] bf16 (O transposed)

  hipLaunchKernelGGL(k_cast_w, dim3(256), dim3(256), 0, stream, Wq, Wk, Wv, Wo, wall);
  hipLaunchKernelGGL(k_stats1, dim3(512), dim3(256), 0, stream, x, part);
  hipLaunchKernelGGL(k_stats2, dim3(2), dim3(256), 0, stream, part, stats);
  hipLaunchKernelGGL(k_norm, dim3(64, 4, 2), dim3(256), 0, stream, x, gw, gb, stats, h);
  hipLaunchKernelGGL(k_qkv, dim3(128, 12), dim3(256), 0, stream, h, wall, bq, bk, bv, qf, kf, vt);
  hipLaunchKernelGGL(k_flash, dim3(128, 16), dim3(256), 0, stream, qf, kf, vt, of2);
  hipLaunchKernelGGL(k_oproj, dim3(256, 4, 2), dim3(256), 0, stream, of2, wall + 3 * 65536, bo, x, out);
}